// Round 7
// baseline (159.649 us; speedup 1.0000x reference)
//
#include <hip/hip_runtime.h>
#include <cstdint>
#include <cstddef>

// ---------------------------------------------------------------------------
// x = mean_i( softmax(q_i K^T / 16) ) @ h   with q = h@Wq, k = h@Wk
//   = sum_j c_j h_j,  c_j = (1/N) sum_i exp(e_ij)/l_i,  l_i = sum_j exp(e_ij)
//
// Round 19: de-convoy the QK^T passes. Evidence: pass cost is 46+-2us across
// FIVE schedule variants (R12/R16/R17/R18) at MfmaUtil ~28 / VALUBusy ~16 /
// zero LDS conflicts -> no pipe saturated; the time is the per-group convoy
// [barrier -> ds_reads -> MFMA -> exp (VALU, serial) -> barrier] where each
// phase idles the other pipes, re-aligned by vmcnt(0)-draining barriers.
// This is the documented m97-structure ceiling; the escape is the T3/T4
// phase schedule. New per-tile pipeline (16 tiles/pass):
//   - 4 x 16KB LDS buffers, depth-2 prefetch (stage t+2 while computing t)
//   - ONE counted s_waitcnt vmcnt(2) + ONE raw s_barrier per tile (never
//     vmcnt(0) in the main loop; vmcnt BEFORE barrier makes every wave's
//     tile-t stage visible grid-wide at barrier exit)
//   - exp epilogue of tile t-1 runs INSIDE tile t's ds_read latency window
//     (after the 8 b-reads issue, before the MFMAs). Old accs die before
//     new accs are born -> allocator reuses, zero extra registers.
//   - s_setprio(1) around MFMA clusters (T5; valid now that phases exist)
// Race audit: stage(t+2) overwrites tile t-2 whose readers finished >= 2
// barriers ago; vmcnt(2) at iter t retires stage(t) (oldest of the 4
// outstanding); tail peeled with vmcnt(0) at t=15.
// proj/finish unchanged (controls). No waves_per_eu (R18: -8us regression).
//
// ws: [0,4MB) q bf16 frag-major | [4MB,8MB) k frag-major | l fp32[8192] |
//     c fp32[8192]
// Frag-major (32x32 MFMA A/B layout) per 32-row tile = 16 KB:
//   elem (i,d): tile i>>5, slot (d>>4)*64 + (i&31) + 32*((d>>3)&1), byte d&7;
//   dword index within tile = a0*64 + lane (lane-linear 16B).
// ---------------------------------------------------------------------------

#define N_ROWS 8192
#define DIM    256

typedef __bf16 bf16x8 __attribute__((ext_vector_type(8)));
typedef unsigned short u16x8 __attribute__((ext_vector_type(8)));
typedef float f32x16 __attribute__((ext_vector_type(16)));

__device__ __forceinline__ uint16_t f2bf(float f) {
    uint32_t u = __float_as_uint(f);
    uint32_t r = (u + 0x7fffu + ((u >> 16) & 1u)) >> 16;   // RTN-even
    return (uint16_t)r;
}

__device__ __forceinline__ float fexp2(float x) {
#if __has_builtin(__builtin_amdgcn_exp2f)
    return __builtin_amdgcn_exp2f(x);                      // v_exp_f32 = 2^x
#else
    return __expf(x * 0.69314718056f);
#endif
}

// async global->LDS, 16B/lane; lds dst is wave-uniform base + lane*16
__device__ __forceinline__ void gld16(const void* gsrc, void* ldst) {
    __builtin_amdgcn_global_load_lds(
        (const __attribute__((address_space(1))) unsigned int*)gsrc,
        (__attribute__((address_space(3))) unsigned int*)ldst, 16, 0, 0);
}

// ---------------------------------------------------------------------------
// Kernel 1 (R11 verbatim): proj. Grid 1024: bid = rt*4 + ph. h staged
// coalesced to LDS (stride-260), W per-lane scalar loads, proven repack.
// Zero-inits l_arr / c_arr / out.
// ---------------------------------------------------------------------------
__global__ __launch_bounds__(256) void proj_kernel(
        const float* __restrict__ h, const float* __restrict__ Wq,
        const float* __restrict__ Wk, uint16_t* __restrict__ qf,
        uint16_t* __restrict__ kf, float* __restrict__ l_arr,
        float* __restrict__ c_arr, float* __restrict__ out) {
    __shared__ alignas(16) float hbf[32 * 260];       // 33.3 KB h stage
    __shared__ alignas(16) uint16_t rep[4][1024];     // 8 KB wave-private repack
    const int tid = threadIdx.x, lane = tid & 63, wave = tid >> 6;
    const int bid = blockIdx.x;
    const int rt = bid >> 2, ph = bid & 3;
    const int which = ph >> 1, p = ph & 1;

    if (bid < 32)       l_arr[bid * 256 + tid] = 0.0f;
    else if (bid < 64)  c_arr[(bid - 32) * 256 + tid] = 0.0f;
    else if (bid == 64) out[tid] = 0.0f;

    const float* __restrict__ W = which ? Wk : Wq;
    uint16_t* __restrict__ dst = which ? kf : qf;
    const float scale = which ? 1.0f : (0.0625f * 1.44269504089f);

    for (int i = tid; i < 2048; i += 256) {
        int r = i >> 6, c = (i & 63) * 4;
        *(float4*)&hbf[r * 260 + c] = *(const float4*)&h[(size_t)(rt * 32 + r) * DIM + c];
    }
    __syncthreads();

    bf16x8 afrag[16];
    {
        const int r = lane & 31;
#pragma unroll
        for (int a0 = 0; a0 < 16; a0++) {
            const int c0 = a0 * 16 + (lane >> 5) * 8;
            float4 f0 = *(const float4*)&hbf[r * 260 + c0];
            float4 f1 = *(const float4*)&hbf[r * 260 + c0 + 4];
            u16x8 f;
            f[0] = f2bf(f0.x); f[1] = f2bf(f0.y); f[2] = f2bf(f0.z); f[3] = f2bf(f0.w);
            f[4] = f2bf(f1.x); f[5] = f2bf(f1.y); f[6] = f2bf(f1.z); f[7] = f2bf(f1.w);
            afrag[a0] = __builtin_bit_cast(bf16x8, f);
        }
    }

    const int ctl = wave;
    const int cl = ctl * 32 + (lane & 31);
    f32x16 acc;
#pragma unroll
    for (int i = 0; i < 16; i++) acc[i] = 0.0f;
#pragma unroll
    for (int a0 = 0; a0 < 16; a0++) {
        const int kb = a0 * 16 + (lane >> 5) * 8;
        u16x8 f;
#pragma unroll
        for (int j = 0; j < 8; j++)
            f[j] = f2bf(W[(size_t)(kb + j) * DIM + p * 128 + cl]);
        acc = __builtin_amdgcn_mfma_f32_32x32x16_bf16(
            afrag[a0], __builtin_bit_cast(bf16x8, f), acc, 0, 0, 0);
    }

    {
        const int dcl = lane & 31;
        const int a0o = dcl >> 4, hi = (dcl >> 3) & 1, jj = dcl & 7;
        const int ilb = 4 * (lane >> 5);
#pragma unroll
        for (int reg = 0; reg < 16; reg++) {
            int il = ilb + (reg & 3) + 8 * (reg >> 2);
            rep[wave][(size_t)((a0o * 64) + il + 32 * hi) * 8 + jj] =
                f2bf(acc[reg] * scale);
        }
        const uint4* rv = (const uint4*)&rep[wave][0];  // wave-local RAW
        uint4* gp = (uint4*)(dst + (size_t)rt * 8192 +
                             (size_t)(p * 4 + ctl) * 1024);
        gp[lane * 2]     = rv[lane * 2];
        gp[lane * 2 + 1] = rv[lane * 2 + 1];
    }
}

// ---------------------------------------------------------------------------
// Kernels 2/3: two QK^T passes, per-tile pipelined (see header). 512 thr,
// grid 256 = 16 rowblocks x 16 colchunks, 1 block/CU. Wave: 2 rowtiles
// resident (q = 128 regs, AGPR-backed), 2 acc chains, 16 coltiles/pass.
// MODE 0: l_i row sums. MODE 1: c_j col sums via c_lds + atomics.
// ---------------------------------------------------------------------------
template <int MODE>
__global__ __launch_bounds__(512) void qk_pass(
        const uint16_t* __restrict__ qf, const uint16_t* __restrict__ kf,
        float* __restrict__ l_arr, float* __restrict__ c_arr) {
    __shared__ alignas(16) uint16_t ktile[4][8192];   // 4 x 16 KB buffers
    __shared__ float c_lds[512];
    const int tid = threadIdx.x, lane = tid & 63, wave = tid >> 6;  // wave 0..7
    const int bid = blockIdx.x;
    const int cc = bid & 15, rb = bid >> 4;           // rb 0..15
    const int t0 = rb * 16 + wave * 2;                // wave's rowtiles t0, t0+1
    const int row0 = t0 * 32;

    // resident q: 2 rowtiles x 16 K-chunks = 128 regs
    const uint4* qp = (const uint4*)qf;
    bf16x8 q0[16], q1[16];
#pragma unroll
    for (int a0 = 0; a0 < 16; a0++) {
        q0[a0] = __builtin_bit_cast(bf16x8, qp[(size_t)t0 * 1024 + a0 * 64 + lane]);
        q1[a0] = __builtin_bit_cast(bf16x8, qp[(size_t)(t0 + 1) * 1024 + a0 * 64 + lane]);
    }

    float rs0[16], rs1[16];   // MODE 0 partials
    float rr0[16], rr1[16];   // MODE 1: 1/(N*l_i)
    if (MODE == 0) {
#pragma unroll
        for (int r = 0; r < 16; r++) { rs0[r] = 0.0f; rs1[r] = 0.0f; }
    } else {
#pragma unroll
        for (int r = 0; r < 16; r++) {
            int ro = (r & 3) + 8 * (r >> 2) + 4 * (lane >> 5);
            rr0[r] = 1.0f / (8192.0f * l_arr[row0 + ro]);
            rr1[r] = 1.0f / (8192.0f * l_arr[row0 + 32 + ro]);
        }
        c_lds[tid] = 0.0f;    // first atomic use is after t=1's barrier
    }

    const char* ksrc = (const char*)kf + (size_t)cc * 16 * 16384;  // 16 tiles
    const char* kw = ksrc + wave * 2048 + lane * 16;   // this wave's 2KB slice

#define STAGE(T) do {                                                        \
        const char* _s = kw + (size_t)(T) * 16384;                           \
        char* _d = (char*)&ktile[(T) & 3][0] + wave * 2048;                  \
        gld16(_s, _d); gld16(_s + 1024, _d + 1024); } while (0)

#define EPILOGUE(TPREV) do {                                                 \
        if (MODE == 0) {                                                     \
            _Pragma("unroll")                                                \
            for (int r = 0; r < 16; r++) {                                   \
                rs0[r] += fexp2(acc0[r]); rs1[r] += fexp2(acc1[r]);          \
            }                                                                \
        } else {                                                             \
            float sv = 0.0f;                                                 \
            _Pragma("unroll")                                                \
            for (int r = 0; r < 16; r++) {                                   \
                sv += fexp2(acc0[r]) * rr0[r];                               \
                sv += fexp2(acc1[r]) * rr1[r];                               \
            }                                                                \
            sv += __shfl_xor(sv, 32);         /* fold row halves per col */  \
            if (lane < 32) atomicAdd(&c_lds[(TPREV) * 32 + lane], sv);       \
        } } while (0)

// One tile: counted-vmcnt + barrier; 8 b-reads; prefetch; epilogue of t-1
// in the read-latency window; 2x16 MFMA clusters under setprio.
#define TILEBODY(T, DO_STAGE, DO_EPI, VM) do {                               \
        asm volatile("s_waitcnt " VM ::: "memory");                          \
        __builtin_amdgcn_s_barrier();                                        \
        const uint16_t* kt = &ktile[(T) & 3][0];                             \
        u16x8 b[8];                                                          \
        _Pragma("unroll")                                                    \
        for (int j = 0; j < 8; j++)                                          \
            b[j] = *(const u16x8*)&kt[(size_t)(j * 64 + lane) * 8];          \
        if (DO_STAGE) STAGE((T) + 2);                                        \
        if (DO_EPI) EPILOGUE((T) - 1);                                       \
        f32x16 na0, na1;                                                     \
        _Pragma("unroll")                                                    \
        for (int i = 0; i < 16; i++) { na0[i] = 0.0f; na1[i] = 0.0f; }       \
        __builtin_amdgcn_s_setprio(1);                                       \
        _Pragma("unroll")                                                    \
        for (int j = 0; j < 8; j++) {                                        \
            bf16x8 bb = __builtin_bit_cast(bf16x8, b[j]);                    \
            na0 = __builtin_amdgcn_mfma_f32_32x32x16_bf16(q0[j], bb, na0, 0, 0, 0); \
            na1 = __builtin_amdgcn_mfma_f32_32x32x16_bf16(q1[j], bb, na1, 0, 0, 0); \
        }                                                                    \
        __builtin_amdgcn_s_setprio(0);                                       \
        _Pragma("unroll")                                                    \
        for (int j = 0; j < 8; j++)                                          \
            b[j] = *(const u16x8*)&kt[(size_t)((j + 8) * 64 + lane) * 8];    \
        __builtin_amdgcn_s_setprio(1);                                       \
        _Pragma("unroll")                                                    \
        for (int j = 0; j < 8; j++) {                                        \
            bf16x8 bb = __builtin_bit_cast(bf16x8, b[j]);                    \
            na0 = __builtin_amdgcn_mfma_f32_32x32x16_bf16(q0[j + 8], bb, na0, 0, 0, 0); \
            na1 = __builtin_amdgcn_mfma_f32_32x32x16_bf16(q1[j + 8], bb, na1, 0, 0, 0); \
        }                                                                    \
        __builtin_amdgcn_s_setprio(0);                                       \
        acc0 = na0; acc1 = na1;                                              \
    } while (0)

    STAGE(0); STAGE(1);                               // depth-2 prologue

    f32x16 acc0, acc1;                                // prev-tile accs
#pragma unroll
    for (int i = 0; i < 16; i++) { acc0[i] = 0.0f; acc1[i] = 0.0f; }

    TILEBODY(0, true, false, "vmcnt(2)");             // stage 2, no epilogue
    for (int t = 1; t <= 13; t++)                     // stage t+2, epi t-1
        TILEBODY(t, true, true, "vmcnt(2)");
    TILEBODY(14, false, true, "vmcnt(2)");            // outstanding {14,15}=4
    TILEBODY(15, false, true, "vmcnt(0)");            // drain tile 15
    EPILOGUE(15);                                     // last tile's epilogue

#undef TILEBODY
#undef EPILOGUE
#undef STAGE

    if (MODE == 0) {
#pragma unroll
        for (int r = 0; r < 16; r++) {
            float v0 = rs0[r], v1 = rs1[r];
            v0 += __shfl_xor(v0, 1);  v0 += __shfl_xor(v0, 2);
            v0 += __shfl_xor(v0, 4);  v0 += __shfl_xor(v0, 8);
            v0 += __shfl_xor(v0, 16);
            v1 += __shfl_xor(v1, 1);  v1 += __shfl_xor(v1, 2);
            v1 += __shfl_xor(v1, 4);  v1 += __shfl_xor(v1, 8);
            v1 += __shfl_xor(v1, 16);
            if ((lane & 31) == 0) {
                int ro = (r & 3) + 8 * (r >> 2) + 4 * (lane >> 5);
                atomicAdd(&l_arr[row0 + ro], v0);
                atomicAdd(&l_arr[row0 + 32 + ro], v1);
            }
        }
    } else {
        __syncthreads();
        atomicAdd(&c_arr[cc * 512 + tid], c_lds[tid]);
    }
}

// ---------------------------------------------------------------------------
// Kernel 4 (R8 verbatim): x = c @ h. 256 blocks x 32 rows, fully unrolled.
// ---------------------------------------------------------------------------
__global__ __launch_bounds__(256) void finish_kernel(
        const float* __restrict__ h, const float* __restrict__ c_arr,
        float* __restrict__ out) {
    const int d = threadIdx.x;
    const int j0 = blockIdx.x * 32;
    float acc = 0.0f;
#pragma unroll
    for (int jj = 0; jj < 32; jj++)
        acc += c_arr[j0 + jj] * h[(size_t)(j0 + jj) * DIM + d];
    atomicAdd(&out[d], acc);
}

// ---------------------------------------------------------------------------
extern "C" void kernel_launch(void* const* d_in, const int* in_sizes, int n_in,
                              void* d_out, int out_size, void* d_ws, size_t ws_size,
                              hipStream_t stream) {
    const float* h  = (const float*)d_in[0];
    const float* Wq = (const float*)d_in[1];
    const float* Wk = (const float*)d_in[2];

    uint16_t* qf = (uint16_t*)d_ws;
    uint16_t* kf = qf + (size_t)N_ROWS * DIM;                  // +4 MB
    float* l_arr = (float*)((char*)d_ws + (size_t)8 * 1024 * 1024);
    float* c_arr = l_arr + N_ROWS;
    float* out = (float*)d_out;

    proj_kernel<<<1024, 256, 0, stream>>>(h, Wq, Wk, qf, kf, l_arr, c_arr, out);
    qk_pass<0><<<256, 512, 0, stream>>>(qf, kf, l_arr, c_arr);
    qk_pass<1><<<256, 512, 0, stream>>>(qf, kf, l_arr, c_arr);
    finish_kernel<<<256, 256, 0, stream>>>(h, c_arr, out);
}